// Round 8
// baseline (409.630 us; speedup 1.0000x reference)
//
#include <hip/hip_runtime.h>
#include <hip/hip_fp16.h>

constexpr int K_DIM = 128;

typedef short bf16x8 __attribute__((ext_vector_type(8)));
typedef float f32x4 __attribute__((ext_vector_type(4)));

#define GLOAD16(g, l) __builtin_amdgcn_global_load_lds( \
    (const __attribute__((address_space(1))) void*)(g), \
    (__attribute__((address_space(3))) void*)(l), 16, 0, 0)

__device__ __forceinline__ unsigned short f2bf(float f) {
  unsigned u = __float_as_uint(f);
  u += 0x7fff + ((u >> 16) & 1);
  return (unsigned short)(u >> 16);
}
__device__ __forceinline__ float bf2f(unsigned short s) {
  return __uint_as_float(((unsigned)s) << 16);
}

// ================= Bucketed CSR build =================
__global__ void zerob_k(int* __restrict__ bcount, int NBr) {
  int t = threadIdx.x;
  if (t < NBr) bcount[t] = 0;
}

__global__ __launch_bounds__(256) void bcount_k(const int* __restrict__ dst, int E,
    int* __restrict__ bcount, int NBr) {
  __shared__ int h[256];
  const int tid = threadIdx.x;
  h[tid] = 0;
  __syncthreads();
  for (int t = blockIdx.x * 256 + tid; t < E; t += gridDim.x * 256)
    atomicAdd(&h[dst[t] >> 8], 1);
  __syncthreads();
  if (tid < NBr && h[tid]) atomicAdd(&bcount[tid], h[tid]);
}

__global__ __launch_bounds__(256) void bscan_k(const int* __restrict__ bcount,
    int* __restrict__ bstart, int* __restrict__ bcursor, int NBr) {
  __shared__ int sh[256];
  const int t = threadIdx.x;
  sh[t] = (t < NBr) ? bcount[t] : 0;
  __syncthreads();
  for (int off = 1; off < 256; off <<= 1) {
    int w = (t >= off) ? sh[t - off] : 0;
    __syncthreads();
    sh[t] += w;
    __syncthreads();
  }
  if (t < NBr) {
    int ex = t ? sh[t - 1] : 0;
    bstart[t] = ex;
    bcursor[t] = ex;
  }
  if (t == NBr - 1) bstart[NBr] = sh[t];
}

__global__ __launch_bounds__(256) void bscatter_k(const int* __restrict__ ei, int E,
    int* __restrict__ bcursor, unsigned* __restrict__ brec, int NBr) {
  __shared__ int h[256];
  __shared__ int base[256];
  const int tid = threadIdx.x;
  h[tid] = 0;
  __syncthreads();
  const int chunk = (E + gridDim.x - 1) / gridDim.x;
  const int s = blockIdx.x * chunk;
  const int e = min(E, s + chunk);
  for (int t = s + tid; t < e; t += 256) atomicAdd(&h[ei[E + t] >> 8], 1);
  __syncthreads();
  if (tid < NBr && h[tid]) base[tid] = atomicAdd(&bcursor[tid], h[tid]);
  __syncthreads();
  for (int t = s + tid; t < e; t += 256) {
    int src = ei[t];
    int d = ei[E + t];
    int bk = d >> 8;
    int p = atomicAdd(&base[bk], 1);
    brec[p] = ((unsigned)src << 8) | (unsigned)(d & 255);
  }
}

__global__ __launch_bounds__(256) void bcsr_k(const unsigned* __restrict__ brec,
    const int* __restrict__ bstart, int n, int E,
    int* __restrict__ rowptr, int* __restrict__ colidx, float* __restrict__ dinv) {
  __shared__ int s_deg[256];
  __shared__ int s_cur[256];
  __shared__ int s_lrp[257];
  const int b = blockIdx.x, tid = threadIdx.x;
  const int node0 = b << 8;
  const int LC = min(256, n - node0);
  const int rs = bstart[b], cnt = bstart[b + 1] - rs;

  s_deg[tid] = (tid < LC) ? 1 : 0;
  __syncthreads();
  for (int i = tid; i < cnt; i += 256) atomicAdd(&s_deg[brec[rs + i] & 255], 1);
  __syncthreads();
  s_cur[tid] = s_deg[tid];
  __syncthreads();
  for (int off = 1; off < 256; off <<= 1) {
    int w = (tid >= off) ? s_cur[tid - off] : 0;
    __syncthreads();
    s_cur[tid] += w;
    __syncthreads();
  }
  s_lrp[tid + 1] = s_cur[tid];
  if (tid == 0) s_lrp[0] = 0;
  __syncthreads();

  const int gbase = rs + node0;
  if (tid < LC) {
    int p = s_lrp[tid];
    colidx[gbase + p] = node0 + tid;
    s_cur[tid] = p + 1;
    rowptr[node0 + tid] = gbase + p;
    dinv[node0 + tid] = rsqrtf((float)(s_lrp[tid + 1] - p));
  }
  __syncthreads();
  for (int i = tid; i < cnt; i += 256) {
    unsigned r = brec[rs + i];
    int p = atomicAdd(&s_cur[r & 255], 1);
    colidx[gbase + p] = (int)(r >> 8);
  }
  if (b == (int)gridDim.x - 1 && tid == 0) rowptr[n] = E + n;
}

// ================= input split: fp32 -> bf16 hi/lo =================
__global__ __launch_bounds__(256) void split_k(const float* __restrict__ x,
    unsigned* __restrict__ zh, unsigned* __restrict__ zl, long total4) {
  long t = (long)blockIdx.x * 256 + threadIdx.x;
  if (t >= total4) return;
  float4 v = reinterpret_cast<const float4*>(x)[t];
  unsigned short hx = f2bf(v.x), hy = f2bf(v.y), hz = f2bf(v.z), hw = f2bf(v.w);
  unsigned short lx = f2bf(v.x - bf2f(hx)), ly = f2bf(v.y - bf2f(hy));
  unsigned short lz = f2bf(v.z - bf2f(hz)), lw = f2bf(v.w - bf2f(hw));
  reinterpret_cast<uint2*>(zh)[t] = make_uint2((unsigned)hx | ((unsigned)hy << 16),
                                               (unsigned)hz | ((unsigned)hw << 16));
  reinterpret_cast<uint2*>(zl)[t] = make_uint2((unsigned)lx | ((unsigned)ly << 16),
                                               (unsigned)lz | ((unsigned)lw << 16));
}

// ================= W prep: fp32 W[k][c] -> bf16 hi/lo transposed Wt[c][k] ======
__global__ __launch_bounds__(256) void wprep_k(
    const float* __restrict__ W1, const float* __restrict__ W2,
    const float* __restrict__ W3, const float* __restrict__ W4,
    unsigned short* __restrict__ wth, unsigned short* __restrict__ wtl) {
  int id = blockIdx.x * 256 + threadIdx.x;
  if (id >= 57344) return;
  const float* W;
  int nout, base, rem;
  if (id < 49152) {
    int l = id / 16384;
    W = (l == 0) ? W1 : (l == 1) ? W2 : W3;
    nout = 128;
    base = l * 16384;
    rem = id - base;
  } else {
    W = W4;
    nout = 64;
    base = 49152;
    rem = id - base;
  }
  int k = rem / nout, c = rem % nout;
  float w = W[k * nout + c];
  unsigned short hi = f2bf(w);
  unsigned short lo = f2bf(w - bf2f(hi));
  wth[base + c * 128 + k] = hi;
  wtl[base + c * 128 + k] = lo;
}

// ================= MFMA GEMM: H = dinv * (Z @ W), 3-term bf16 split =========
// 64-row blocks, 4 waves in 2x2 (rowhalf x colhalf). B entirely in registers;
// A staged ONCE (full K) into XOR-swizzled LDS (linear dest, pre-swizzled src).
// For NOUT=128 output H is feature-split: H[col>>6][row][col&63] (fp16).
template<int NOUT>
__global__ __launch_bounds__(256, 2) void gemm_mfma_k(
    const unsigned short* __restrict__ Zh, const unsigned short* __restrict__ Zl,
    const unsigned short* __restrict__ Wh, const unsigned short* __restrict__ Wl,
    const float* __restrict__ dinv, __half* __restrict__ H, int n) {
  constexpr int CT = NOUT / 32;          // col-tiles per wave
  __shared__ unsigned short Ah[64 * 128];
  __shared__ unsigned short Al[64 * 128];
  const int tid = threadIdx.x;
  const int lane = tid & 63;
  const int w = tid >> 6;
  const int r16 = lane & 15;
  const int kb = lane >> 4;
  const int row0 = blockIdx.x * 64;
  const int rbase = (w & 1) * 32;
  const int cb = (w >> 1) * (NOUT / 2);

  // B preload into registers (per-lane strided global loads, L2-hot)
  bf16x8 bh[CT][4], bl[CT][4];
  #pragma unroll
  for (int t = 0; t < CT; ++t)
    #pragma unroll
    for (int kc = 0; kc < 4; ++kc) {
      size_t boff = (size_t)(cb + t * 16 + r16) * 128 + kc * 32 + kb * 8;
      bh[t][kc] = *(const bf16x8*)&Wh[boff];
      bl[t][kc] = *(const bf16x8*)&Wl[boff];
    }

  // stage A: dest slot i = it*256 + tid (linear); row r=i>>4, k-oct k2=(i&15)^(r&7)
  char* AhB = (char*)Ah;
  char* AlB = (char*)Al;
  #pragma unroll
  for (int it = 0; it < 4; ++it) {
    int i = it * 256 + tid;
    int r = i >> 4;
    int k2 = (i & 15) ^ (r & 7);
    int rc = row0 + r; rc = (rc < n) ? rc : (n - 1);
    GLOAD16(Zh + (size_t)rc * 128 + k2 * 8, AhB + it * 4096 + w * 1024);
    GLOAD16(Zl + (size_t)rc * 128 + k2 * 8, AlB + it * 4096 + w * 1024);
  }
  __syncthreads();

  f32x4 acc[2][CT];
  #pragma unroll
  for (int rf = 0; rf < 2; ++rf)
    #pragma unroll
    for (int t = 0; t < CT; ++t)
      #pragma unroll
      for (int q = 0; q < 4; ++q) acc[rf][t][q] = 0.f;

  const int r0 = rbase + r16;
  const int r1 = rbase + 16 + r16;
  const int sw = r16 & 7;                 // (r0&7) == (r1&7) == r16&7
  #pragma unroll
  for (int kc = 0; kc < 4; ++kc) {
    int k2s = (kc * 4 + kb) ^ sw;
    bf16x8 ah0 = *(const bf16x8*)(AhB + r0 * 256 + k2s * 16);
    bf16x8 al0 = *(const bf16x8*)(AlB + r0 * 256 + k2s * 16);
    bf16x8 ah1 = *(const bf16x8*)(AhB + r1 * 256 + k2s * 16);
    bf16x8 al1 = *(const bf16x8*)(AlB + r1 * 256 + k2s * 16);
    #pragma unroll
    for (int t = 0; t < CT; ++t) {
      acc[0][t] = __builtin_amdgcn_mfma_f32_16x16x32_bf16(ah0, bh[t][kc], acc[0][t], 0, 0, 0);
      acc[0][t] = __builtin_amdgcn_mfma_f32_16x16x32_bf16(ah0, bl[t][kc], acc[0][t], 0, 0, 0);
      acc[0][t] = __builtin_amdgcn_mfma_f32_16x16x32_bf16(al0, bh[t][kc], acc[0][t], 0, 0, 0);
      acc[1][t] = __builtin_amdgcn_mfma_f32_16x16x32_bf16(ah1, bh[t][kc], acc[1][t], 0, 0, 0);
      acc[1][t] = __builtin_amdgcn_mfma_f32_16x16x32_bf16(ah1, bl[t][kc], acc[1][t], 0, 0, 0);
      acc[1][t] = __builtin_amdgcn_mfma_f32_16x16x32_bf16(al1, bh[t][kc], acc[1][t], 0, 0, 0);
    }
  }

  // epilogue: H = dinv*acc (fp16); C/D: col=r16, row=kb*4+q
  #pragma unroll
  for (int rf = 0; rf < 2; ++rf)
    #pragma unroll
    for (int q = 0; q < 4; ++q) {
      int grow = row0 + rbase + rf * 16 + kb * 4 + q;
      if (grow < n) {
        float dsc = dinv[grow];
        #pragma unroll
        for (int t = 0; t < CT; ++t) {
          int col = cb + t * 16 + r16;
          size_t dst;
          if constexpr (NOUT == 128)
            dst = (size_t)(col >> 6) * ((size_t)n * 64) + (size_t)grow * 64 + (col & 63);
          else
            dst = (size_t)grow * 64 + col;
          H[dst] = __float2half(dsc * acc[rf][t][q]);
        }
      }
    }
}

// ================= CSR aggregation, one 64-feature half per launch ============
// Wave = 1 node; 2 edge-groups of 32 lanes (lane&31 = feature pair).
// H prescaled by dinv[src]: out = dinv[i]*sum H'[c] + b ; relu + bf16 split.
__global__ __launch_bounds__(256) void agg128h_k(const __half* __restrict__ Hh,
    const int* __restrict__ rowptr, const int* __restrict__ colidx,
    const float* __restrict__ dinv, const float* __restrict__ bias,
    unsigned short* __restrict__ Zhd, unsigned short* __restrict__ Zld, int n) {
  const int wave = threadIdx.x >> 6;
  const int lane = threadIdx.x & 63;
  const int node = blockIdx.x * 4 + wave;
  if (node >= n) return;
  const int l31 = lane & 31;
  const int g = lane >> 5;
  const int s = rowptr[node], e = rowptr[node + 1];
  const __half2* H2 = reinterpret_cast<const __half2*>(Hh);

  float ax = 0.f, ay = 0.f;
  for (int base = s; base < e; base += 64) {
    int m = e - base;
    int c = __builtin_nontemporal_load(&colidx[base + ((lane < m) ? lane : 0)]);
    int kmax = (m < 64) ? m : 64;
    int k = 0;
    for (; k + 15 < kmax; k += 16) {
      int cc[8]; float2 hh[8];
      #pragma unroll
      for (int u = 0; u < 8; ++u) cc[u] = __shfl(c, k + 2 * u + g);
      #pragma unroll
      for (int u = 0; u < 8; ++u) hh[u] = __half22float2(H2[(size_t)cc[u] * 32 + l31]);
      #pragma unroll
      for (int u = 0; u < 8; ++u) { ax += hh[u].x; ay += hh[u].y; }
    }
    for (; k < kmax; k += 2) {
      int kk = k + g;
      int ck = __shfl(c, (kk < kmax) ? kk : k);
      if (kk < kmax) {
        float2 hv = __half22float2(H2[(size_t)ck * 32 + l31]);
        ax += hv.x; ay += hv.y;
      }
    }
  }
  ax += __shfl_xor(ax, 32);
  ay += __shfl_xor(ay, 32);
  if (g == 0) {
    float d = dinv[node];
    float2 b2 = reinterpret_cast<const float2*>(bias)[l31];
    float ox = fmaxf(fmaf(d, ax, b2.x), 0.f);
    float oy = fmaxf(fmaf(d, ay, b2.y), 0.f);
    unsigned short hx = f2bf(ox), hy = f2bf(oy);
    unsigned short lx = f2bf(ox - bf2f(hx)), ly = f2bf(oy - bf2f(hy));
    unsigned vh = (unsigned)hx | ((unsigned)hy << 16);
    unsigned vl = (unsigned)lx | ((unsigned)ly << 16);
    __builtin_nontemporal_store(vh, (unsigned*)(Zhd + (size_t)node * 128) + l31);
    __builtin_nontemporal_store(vl, (unsigned*)(Zld + (size_t)node * 128) + l31);
  }
}

// final layer: 64-wide, fp32 out, no relu
__global__ __launch_bounds__(256) void agg64_k(const __half* __restrict__ H,
    const int* __restrict__ rowptr, const int* __restrict__ colidx,
    const float* __restrict__ dinv, const float* __restrict__ bias,
    float* __restrict__ out, int n) {
  const int wave = threadIdx.x >> 6;
  const int lane = threadIdx.x & 63;
  const int node = blockIdx.x * 4 + wave;
  if (node >= n) return;
  const int s = rowptr[node], e = rowptr[node + 1];

  float a0 = 0.f;
  for (int base = s; base < e; base += 64) {
    int m = e - base;
    int c = __builtin_nontemporal_load(&colidx[base + ((lane < m) ? lane : 0)]);
    int kmax = (m < 64) ? m : 64;
    int k = 0;
    for (; k + 7 < kmax; k += 8) {
      int cc[8];
      float hh[8];
      #pragma unroll
      for (int u = 0; u < 8; ++u) cc[u] = __shfl(c, k + u);
      #pragma unroll
      for (int u = 0; u < 8; ++u) hh[u] = __half2float(H[(size_t)cc[u] * 64 + lane]);
      #pragma unroll
      for (int u = 0; u < 8; ++u) a0 += hh[u];
    }
    for (; k < kmax; ++k) {
      int ck = __shfl(c, k);
      a0 += __half2float(H[(size_t)ck * 64 + lane]);
    }
  }
  float o = fmaf(dinv[node], a0, bias[lane]);
  __builtin_nontemporal_store(o, &out[(size_t)node * 64 + lane]);
}

extern "C" void kernel_launch(void* const* d_in, const int* in_sizes, int n_in,
                              void* d_out, int out_size, void* d_ws, size_t ws_size,
                              hipStream_t stream) {
  const int n = in_sizes[0] / K_DIM;   // 50000
  const int E = in_sizes[1] / 2;       // 1600000
  const int NBr = (n + 255) >> 8;

  const float* x  = (const float*)d_in[0];
  const int*   ei = (const int*)d_in[1];
  const float* W1 = (const float*)d_in[2];
  const float* b1 = (const float*)d_in[3];
  const float* W2 = (const float*)d_in[4];
  const float* b2 = (const float*)d_in[5];
  const float* W3 = (const float*)d_in[6];
  const float* b3 = (const float*)d_in[7];
  const float* W4 = (const float*)d_in[8];
  const float* b4 = (const float*)d_in[9];
  float* out = (float*)d_out;

  char* ws = (char*)d_ws;
  size_t off = 0;
  auto alloc = [&](size_t bytes) -> void* {
    void* p = ws + off;
    off += (bytes + 255) & ~(size_t)255;
    return p;
  };
  int*      bcount  = (int*)     alloc(256 * 4);
  int*      bstart  = (int*)     alloc(257 * 4);
  int*      bcursor = (int*)     alloc(256 * 4);
  unsigned* brec    = (unsigned*)alloc((size_t)E * 4);
  int*      rowptr  = (int*)     alloc((size_t)(n + 1) * 4);
  int*      colidx  = (int*)     alloc((size_t)(E + n) * 4);
  float*    dinv    = (float*)   alloc((size_t)n * 4);
  unsigned short* Zh = (unsigned short*)alloc((size_t)n * 128 * 2);
  unsigned short* Zl = (unsigned short*)alloc((size_t)n * 128 * 2);
  __half*   hH      = (__half*)  alloc((size_t)n * 128 * 2);
  unsigned short* wth = (unsigned short*)alloc((size_t)57344 * 2);
  unsigned short* wtl = (unsigned short*)alloc((size_t)57344 * 2);

  // CSR build
  zerob_k<<<1, 256, 0, stream>>>(bcount, NBr);
  bcount_k<<<512, 256, 0, stream>>>(ei + E, E, bcount, NBr);
  bscan_k<<<1, 256, 0, stream>>>(bcount, bstart, bcursor, NBr);
  bscatter_k<<<256, 256, 0, stream>>>(ei, E, bcursor, brec, NBr);
  bcsr_k<<<NBr, 256, 0, stream>>>(brec, bstart, n, E, rowptr, colidx, dinv);

  // input split + weight prep
  const long total4 = (long)n * 32;
  split_k<<<(int)((total4 + 255) / 256), 256, 0, stream>>>(x, (unsigned*)Zh, (unsigned*)Zl, total4);
  wprep_k<<<224, 256, 0, stream>>>(W1, W2, W3, W4, wth, wtl);

  const int gb = (n + 63) / 64;   // 782 blocks
  const int ab = (n + 3) / 4;

  const float* biases[3] = {b1, b2, b3};
  const unsigned short* wh[3] = {wth, wth + 16384, wth + 32768};
  const unsigned short* wl[3] = {wtl, wtl + 16384, wtl + 32768};

  for (int l = 0; l < 3; ++l) {
    gemm_mfma_k<128><<<gb, 256, 0, stream>>>(Zh, Zl, wh[l], wl[l], dinv, hH, n);
    for (int h = 0; h < 2; ++h) {
      agg128h_k<<<ab, 256, 0, stream>>>(hH + (size_t)h * n * 64, rowptr, colidx,
                                        dinv, biases[l] + h * 64,
                                        Zh + h * 64, Zl + h * 64, n);
    }
  }
  // layer 4 (128 -> 64)
  gemm_mfma_k<64><<<gb, 256, 0, stream>>>(Zh, Zl, wth + 49152, wtl + 49152, dinv, hH, n);
  agg64_k<<<ab, 256, 0, stream>>>(hH, rowptr, colidx, dinv, b4, out, n);
}

// Round 9
// 322.697 us; speedup vs baseline: 1.2694x; 1.2694x over previous
//
#include <hip/hip_runtime.h>
#include <hip/hip_fp16.h>

constexpr int K_DIM = 128;

typedef short bf16x8 __attribute__((ext_vector_type(8)));
typedef float f32x4 __attribute__((ext_vector_type(4)));

#define GLOAD16(g, l) __builtin_amdgcn_global_load_lds( \
    (const __attribute__((address_space(1))) void*)(g), \
    (__attribute__((address_space(3))) void*)(l), 16, 0, 0)

__device__ __forceinline__ unsigned short f2bf(float f) {
  unsigned u = __float_as_uint(f);
  u += 0x7fff + ((u >> 16) & 1);
  return (unsigned short)(u >> 16);
}
__device__ __forceinline__ float bf2f(unsigned short s) {
  return __uint_as_float(((unsigned)s) << 16);
}

// ================= Bucketed CSR build =================
__global__ void zerob_k(int* __restrict__ bcount, int NBr) {
  int t = threadIdx.x;
  if (t < NBr) bcount[t] = 0;
}

__global__ __launch_bounds__(256) void bcount_k(const int* __restrict__ dst, int E,
    int* __restrict__ bcount, int NBr) {
  __shared__ int h[256];
  const int tid = threadIdx.x;
  h[tid] = 0;
  __syncthreads();
  for (int t = blockIdx.x * 256 + tid; t < E; t += gridDim.x * 256)
    atomicAdd(&h[dst[t] >> 8], 1);
  __syncthreads();
  if (tid < NBr && h[tid]) atomicAdd(&bcount[tid], h[tid]);
}

__global__ __launch_bounds__(256) void bscan_k(const int* __restrict__ bcount,
    int* __restrict__ bstart, int* __restrict__ bcursor, int NBr) {
  __shared__ int sh[256];
  const int t = threadIdx.x;
  sh[t] = (t < NBr) ? bcount[t] : 0;
  __syncthreads();
  for (int off = 1; off < 256; off <<= 1) {
    int w = (t >= off) ? sh[t - off] : 0;
    __syncthreads();
    sh[t] += w;
    __syncthreads();
  }
  if (t < NBr) {
    int ex = t ? sh[t - 1] : 0;
    bstart[t] = ex;
    bcursor[t] = ex;
  }
  if (t == NBr - 1) bstart[NBr] = sh[t];
}

__global__ __launch_bounds__(256) void bscatter_k(const int* __restrict__ ei, int E,
    int* __restrict__ bcursor, unsigned* __restrict__ brec, int NBr) {
  __shared__ int h[256];
  __shared__ int base[256];
  const int tid = threadIdx.x;
  h[tid] = 0;
  __syncthreads();
  const int chunk = (E + gridDim.x - 1) / gridDim.x;
  const int s = blockIdx.x * chunk;
  const int e = min(E, s + chunk);
  for (int t = s + tid; t < e; t += 256) atomicAdd(&h[ei[E + t] >> 8], 1);
  __syncthreads();
  if (tid < NBr && h[tid]) base[tid] = atomicAdd(&bcursor[tid], h[tid]);
  __syncthreads();
  for (int t = s + tid; t < e; t += 256) {
    int src = ei[t];
    int d = ei[E + t];
    int bk = d >> 8;
    int p = atomicAdd(&base[bk], 1);
    brec[p] = ((unsigned)src << 8) | (unsigned)(d & 255);
  }
}

__global__ __launch_bounds__(256) void bcsr_k(const unsigned* __restrict__ brec,
    const int* __restrict__ bstart, int n, int E,
    int* __restrict__ rowptr, int* __restrict__ colidx, float* __restrict__ dinv) {
  __shared__ int s_deg[256];
  __shared__ int s_cur[256];
  __shared__ int s_lrp[257];
  const int b = blockIdx.x, tid = threadIdx.x;
  const int node0 = b << 8;
  const int LC = min(256, n - node0);
  const int rs = bstart[b], cnt = bstart[b + 1] - rs;

  s_deg[tid] = (tid < LC) ? 1 : 0;
  __syncthreads();
  for (int i = tid; i < cnt; i += 256) atomicAdd(&s_deg[brec[rs + i] & 255], 1);
  __syncthreads();
  s_cur[tid] = s_deg[tid];
  __syncthreads();
  for (int off = 1; off < 256; off <<= 1) {
    int w = (tid >= off) ? s_cur[tid - off] : 0;
    __syncthreads();
    s_cur[tid] += w;
    __syncthreads();
  }
  s_lrp[tid + 1] = s_cur[tid];
  if (tid == 0) s_lrp[0] = 0;
  __syncthreads();

  const int gbase = rs + node0;
  if (tid < LC) {
    int p = s_lrp[tid];
    colidx[gbase + p] = node0 + tid;
    s_cur[tid] = p + 1;
    rowptr[node0 + tid] = gbase + p;
    dinv[node0 + tid] = rsqrtf((float)(s_lrp[tid + 1] - p));
  }
  __syncthreads();
  for (int i = tid; i < cnt; i += 256) {
    unsigned r = brec[rs + i];
    int p = atomicAdd(&s_cur[r & 255], 1);
    colidx[gbase + p] = (int)(r >> 8);
  }
  if (b == (int)gridDim.x - 1 && tid == 0) rowptr[n] = E + n;
}

// ================= input split: fp32 -> bf16 hi/lo =================
__global__ __launch_bounds__(256) void split_k(const float* __restrict__ x,
    unsigned* __restrict__ zh, unsigned* __restrict__ zl, long total4) {
  long t = (long)blockIdx.x * 256 + threadIdx.x;
  if (t >= total4) return;
  float4 v = reinterpret_cast<const float4*>(x)[t];
  unsigned short hx = f2bf(v.x), hy = f2bf(v.y), hz = f2bf(v.z), hw = f2bf(v.w);
  unsigned short lx = f2bf(v.x - bf2f(hx)), ly = f2bf(v.y - bf2f(hy));
  unsigned short lz = f2bf(v.z - bf2f(hz)), lw = f2bf(v.w - bf2f(hw));
  reinterpret_cast<uint2*>(zh)[t] = make_uint2((unsigned)hx | ((unsigned)hy << 16),
                                               (unsigned)hz | ((unsigned)hw << 16));
  reinterpret_cast<uint2*>(zl)[t] = make_uint2((unsigned)lx | ((unsigned)ly << 16),
                                               (unsigned)lz | ((unsigned)lw << 16));
}

// ================= W prep: fp32 W[k][c] -> bf16 hi/lo transposed Wt[c][k] ======
__global__ __launch_bounds__(256) void wprep_k(
    const float* __restrict__ W1, const float* __restrict__ W2,
    const float* __restrict__ W3, const float* __restrict__ W4,
    unsigned short* __restrict__ wth, unsigned short* __restrict__ wtl) {
  int id = blockIdx.x * 256 + threadIdx.x;
  if (id >= 57344) return;
  const float* W;
  int nout, base, rem;
  if (id < 49152) {
    int l = id / 16384;
    W = (l == 0) ? W1 : (l == 1) ? W2 : W3;
    nout = 128;
    base = l * 16384;
    rem = id - base;
  } else {
    W = W4;
    nout = 64;
    base = 49152;
    rem = id - base;
  }
  int k = rem / nout, c = rem % nout;
  float w = W[k * nout + c];
  unsigned short hi = f2bf(w);
  unsigned short lo = f2bf(w - bf2f(hi));
  wth[base + c * 128 + k] = hi;
  wtl[base + c * 128 + k] = lo;
}

// ================= MFMA GEMM: H[r] = dinv[r] * (Z @ W)[r]  (3-term bf16 split) ==
// 64-row tiles, 4 waves, wave = 16 rows x NOUT cols. LDS XOR-oct-swizzled:
// source k-oct q of row r stored at dest oct q ^ g(r), g(r) = (r + (r>>2)) & 3.
// (dest stays linear for global_load_lds; source address pre-permuted; reads
// use the same involution -> 16 row-stride lanes cover all 8 bank-group starts
// = 2-way aliasing = free.)
template<int NOUT>
__global__ __launch_bounds__(256) void gemm_mfma_k(
    const unsigned short* __restrict__ Zh, const unsigned short* __restrict__ Zl,
    const unsigned short* __restrict__ Wh, const unsigned short* __restrict__ Wl,
    const float* __restrict__ dinv, __half* __restrict__ H, int n) {
  constexpr int NT = NOUT / 16;
  __shared__ unsigned short Ah[64][32];
  __shared__ unsigned short Al[64][32];
  __shared__ unsigned short Bh[NOUT][32];
  __shared__ unsigned short Bl[NOUT][32];
  const int tid = threadIdx.x;
  const int lane = tid & 63;
  const int w = tid >> 6;
  const int r16 = lane & 15;
  const int kb = lane >> 4;
  const int row0 = blockIdx.x * 64;
  const int sw = (r16 + (r16 >> 2)) & 3;   // g(row) for all rows this lane reads

  f32x4 acc[NT];
  #pragma unroll
  for (int t = 0; t < NT; ++t)
    #pragma unroll
    for (int q = 0; q < 4; ++q) acc[t][q] = 0.f;

  char* AhB = (char*)&Ah[0][0];
  char* AlB = (char*)&Al[0][0];
  char* BhB = (char*)&Bh[0][0];
  char* BlB = (char*)&Bl[0][0];

  for (int kc = 0; kc < 128; kc += 32) {
    __syncthreads();
    {
      // A: slot=tid -> row r=tid>>2, dest oct j=tid&3, src oct q=j^g(r)
      int r = tid >> 2;
      int q = (tid & 3) ^ ((r + (r >> 2)) & 3);
      int rc = row0 + r; rc = (rc < n) ? rc : (n - 1);
      GLOAD16(Zh + (size_t)rc * 128 + kc + q * 8, AhB + w * 1024);
      GLOAD16(Zl + (size_t)rc * 128 + kc + q * 8, AlB + w * 1024);
    }
    {
      // B: slot=tid (+256 for NOUT=128) -> col c=slot>>2, same swizzle
      int c = tid >> 2;
      int q = (tid & 3) ^ ((c + (c >> 2)) & 3);
      GLOAD16(Wh + (size_t)c * 128 + kc + q * 8, BhB + w * 1024);
      GLOAD16(Wl + (size_t)c * 128 + kc + q * 8, BlB + w * 1024);
      if constexpr (NOUT == 128) {
        int i1 = tid + 256;
        int c1 = i1 >> 2;
        int q1 = (i1 & 3) ^ ((c1 + (c1 >> 2)) & 3);
        GLOAD16(Wh + (size_t)c1 * 128 + kc + q1 * 8, BhB + 4096 + w * 1024);
        GLOAD16(Wl + (size_t)c1 * 128 + kc + q1 * 8, BlB + 4096 + w * 1024);
      }
    }
    __syncthreads();

    const int ao = (kb ^ sw) * 8;
    bf16x8 ah = *(const bf16x8*)&Ah[w * 16 + r16][ao];
    bf16x8 al = *(const bf16x8*)&Al[w * 16 + r16][ao];
    #pragma unroll
    for (int t = 0; t < NT; ++t) {
      bf16x8 bh = *(const bf16x8*)&Bh[t * 16 + r16][ao];
      bf16x8 bl = *(const bf16x8*)&Bl[t * 16 + r16][ao];
      acc[t] = __builtin_amdgcn_mfma_f32_16x16x32_bf16(ah, bh, acc[t], 0, 0, 0);
      acc[t] = __builtin_amdgcn_mfma_f32_16x16x32_bf16(ah, bl, acc[t], 0, 0, 0);
      acc[t] = __builtin_amdgcn_mfma_f32_16x16x32_bf16(al, bh, acc[t], 0, 0, 0);
    }
  }

  // epilogue: H[row] = dinv[row] * acc (fp16); C/D: col=r16, row=kb*4+q
  #pragma unroll
  for (int q = 0; q < 4; ++q) {
    int grow = row0 + w * 16 + kb * 4 + q;
    if (grow < n) {
      float dsc = dinv[grow];
      #pragma unroll
      for (int t = 0; t < NT; ++t)
        H[(size_t)grow * NOUT + t * 16 + r16] = __float2half(dsc * acc[t][q]);
    }
  }
}

// ================= CSR aggregation (prescaled H, shfl-broadcast) =============
// Wave = 1 node, lane = feature pair. H prescaled by dinv[src]:
// out_i = dinv[i] * sum_c H'[c] + b ; relu + bf16 hi/lo split store.
__global__ __launch_bounds__(256) void agg128_k(const __half* __restrict__ H,
    const int* __restrict__ rowptr, const int* __restrict__ colidx,
    const float* __restrict__ dinv, const float* __restrict__ bias,
    unsigned* __restrict__ Zh, unsigned* __restrict__ Zl, int n) {
  const int wave = threadIdx.x >> 6;
  const int lane = threadIdx.x & 63;
  const int node = blockIdx.x * 4 + wave;
  if (node >= n) return;
  const int s = rowptr[node], e = rowptr[node + 1];
  const __half2* H2 = reinterpret_cast<const __half2*>(H);

  float ax = 0.f, ay = 0.f;
  for (int base = s; base < e; base += 64) {
    int m = e - base;
    int c = __builtin_nontemporal_load(&colidx[base + ((lane < m) ? lane : 0)]);
    int kmax = (m < 64) ? m : 64;
    int k = 0;
    for (; k + 7 < kmax; k += 8) {
      int cc[8];
      float2 hh[8];
      #pragma unroll
      for (int u = 0; u < 8; ++u) cc[u] = __shfl(c, k + u);
      #pragma unroll
      for (int u = 0; u < 8; ++u) hh[u] = __half22float2(H2[(size_t)cc[u] * 64 + lane]);
      #pragma unroll
      for (int u = 0; u < 8; ++u) { ax += hh[u].x; ay += hh[u].y; }
    }
    for (; k < kmax; ++k) {
      int ck = __shfl(c, k);
      float2 h = __half22float2(H2[(size_t)ck * 64 + lane]);
      ax += h.x;
      ay += h.y;
    }
  }
  float d = dinv[node];
  float2 b2 = reinterpret_cast<const float2*>(bias)[lane];
  float ox = fmaxf(fmaf(d, ax, b2.x), 0.f);
  float oy = fmaxf(fmaf(d, ay, b2.y), 0.f);
  unsigned short hx = f2bf(ox), hy = f2bf(oy);
  unsigned short lx = f2bf(ox - bf2f(hx)), ly = f2bf(oy - bf2f(hy));
  unsigned vh = (unsigned)hx | ((unsigned)hy << 16);
  unsigned vl = (unsigned)lx | ((unsigned)ly << 16);
  __builtin_nontemporal_store(vh, &Zh[(size_t)node * 64 + lane]);
  __builtin_nontemporal_store(vl, &Zl[(size_t)node * 64 + lane]);
}

// final layer: 64-wide, fp32 out, no relu
__global__ __launch_bounds__(256) void agg64_k(const __half* __restrict__ H,
    const int* __restrict__ rowptr, const int* __restrict__ colidx,
    const float* __restrict__ dinv, const float* __restrict__ bias,
    float* __restrict__ out, int n) {
  const int wave = threadIdx.x >> 6;
  const int lane = threadIdx.x & 63;
  const int node = blockIdx.x * 4 + wave;
  if (node >= n) return;
  const int s = rowptr[node], e = rowptr[node + 1];

  float a0 = 0.f;
  for (int base = s; base < e; base += 64) {
    int m = e - base;
    int c = __builtin_nontemporal_load(&colidx[base + ((lane < m) ? lane : 0)]);
    int kmax = (m < 64) ? m : 64;
    int k = 0;
    for (; k + 7 < kmax; k += 8) {
      int cc[8];
      float hh[8];
      #pragma unroll
      for (int u = 0; u < 8; ++u) cc[u] = __shfl(c, k + u);
      #pragma unroll
      for (int u = 0; u < 8; ++u) hh[u] = __half2float(H[(size_t)cc[u] * 64 + lane]);
      #pragma unroll
      for (int u = 0; u < 8; ++u) a0 += hh[u];
    }
    for (; k < kmax; ++k) {
      int ck = __shfl(c, k);
      a0 += __half2float(H[(size_t)ck * 64 + lane]);
    }
  }
  float o = fmaf(dinv[node], a0, bias[lane]);
  __builtin_nontemporal_store(o, &out[(size_t)node * 64 + lane]);
}

extern "C" void kernel_launch(void* const* d_in, const int* in_sizes, int n_in,
                              void* d_out, int out_size, void* d_ws, size_t ws_size,
                              hipStream_t stream) {
  const int n = in_sizes[0] / K_DIM;   // 50000
  const int E = in_sizes[1] / 2;       // 1600000
  const int NBr = (n + 255) >> 8;

  const float* x  = (const float*)d_in[0];
  const int*   ei = (const int*)d_in[1];
  const float* W1 = (const float*)d_in[2];
  const float* b1 = (const float*)d_in[3];
  const float* W2 = (const float*)d_in[4];
  const float* b2 = (const float*)d_in[5];
  const float* W3 = (const float*)d_in[6];
  const float* b3 = (const float*)d_in[7];
  const float* W4 = (const float*)d_in[8];
  const float* b4 = (const float*)d_in[9];
  float* out = (float*)d_out;

  char* ws = (char*)d_ws;
  size_t off = 0;
  auto alloc = [&](size_t bytes) -> void* {
    void* p = ws + off;
    off += (bytes + 255) & ~(size_t)255;
    return p;
  };
  int*      bcount  = (int*)     alloc(256 * 4);
  int*      bstart  = (int*)     alloc(257 * 4);
  int*      bcursor = (int*)     alloc(256 * 4);
  unsigned* brec    = (unsigned*)alloc((size_t)E * 4);
  int*      rowptr  = (int*)     alloc((size_t)(n + 1) * 4);
  int*      colidx  = (int*)     alloc((size_t)(E + n) * 4);
  float*    dinv    = (float*)   alloc((size_t)n * 4);
  unsigned short* Zh = (unsigned short*)alloc((size_t)n * 128 * 2);
  unsigned short* Zl = (unsigned short*)alloc((size_t)n * 128 * 2);
  __half*   hH      = (__half*)  alloc((size_t)n * 128 * 2);
  unsigned short* wth = (unsigned short*)alloc((size_t)57344 * 2);
  unsigned short* wtl = (unsigned short*)alloc((size_t)57344 * 2);

  // CSR build
  zerob_k<<<1, 256, 0, stream>>>(bcount, NBr);
  bcount_k<<<512, 256, 0, stream>>>(ei + E, E, bcount, NBr);
  bscan_k<<<1, 256, 0, stream>>>(bcount, bstart, bcursor, NBr);
  bscatter_k<<<256, 256, 0, stream>>>(ei, E, bcursor, brec, NBr);
  bcsr_k<<<NBr, 256, 0, stream>>>(brec, bstart, n, E, rowptr, colidx, dinv);

  // input split + weight prep
  const long total4 = (long)n * 32;
  split_k<<<(int)((total4 + 255) / 256), 256, 0, stream>>>(x, (unsigned*)Zh, (unsigned*)Zl, total4);
  wprep_k<<<224, 256, 0, stream>>>(W1, W2, W3, W4, wth, wtl);

  const int gb = (n + 63) / 64;   // 782 blocks
  const int ab = (n + 3) / 4;

  // layer 1
  gemm_mfma_k<128><<<gb, 256, 0, stream>>>(Zh, Zl, wth, wtl, dinv, hH, n);
  agg128_k<<<ab, 256, 0, stream>>>(hH, rowptr, colidx, dinv, b1, (unsigned*)Zh, (unsigned*)Zl, n);
  // layer 2
  gemm_mfma_k<128><<<gb, 256, 0, stream>>>(Zh, Zl, wth + 16384, wtl + 16384, dinv, hH, n);
  agg128_k<<<ab, 256, 0, stream>>>(hH, rowptr, colidx, dinv, b2, (unsigned*)Zh, (unsigned*)Zl, n);
  // layer 3
  gemm_mfma_k<128><<<gb, 256, 0, stream>>>(Zh, Zl, wth + 32768, wtl + 32768, dinv, hH, n);
  agg128_k<<<ab, 256, 0, stream>>>(hH, rowptr, colidx, dinv, b3, (unsigned*)Zh, (unsigned*)Zl, n);
  // layer 4 (128 -> 64)
  gemm_mfma_k<64><<<gb, 256, 0, stream>>>(Zh, Zl, wth + 49152, wtl + 49152, dinv, hH, n);
  agg64_k<<<ab, 256, 0, stream>>>(hH, rowptr, colidx, dinv, b4, out, n);
}

// Round 10
// 317.030 us; speedup vs baseline: 1.2921x; 1.0179x over previous
//
#include <hip/hip_runtime.h>
#include <hip/hip_fp16.h>

constexpr int K_DIM = 128;

typedef _Float16 f16x8 __attribute__((ext_vector_type(8)));
typedef float f32x4 __attribute__((ext_vector_type(4)));

#define GLOAD16(g, l) __builtin_amdgcn_global_load_lds( \
    (const __attribute__((address_space(1))) void*)(g), \
    (__attribute__((address_space(3))) void*)(l), 16, 0, 0)

// ================= Bucketed CSR build =================
__global__ void zerob_k(int* __restrict__ bcount, int NBr) {
  int t = threadIdx.x;
  if (t < NBr) bcount[t] = 0;
}

__global__ __launch_bounds__(256) void bcount_k(const int* __restrict__ dst, int E,
    int* __restrict__ bcount, int NBr) {
  __shared__ int h[256];
  const int tid = threadIdx.x;
  h[tid] = 0;
  __syncthreads();
  for (int t = blockIdx.x * 256 + tid; t < E; t += gridDim.x * 256)
    atomicAdd(&h[dst[t] >> 8], 1);
  __syncthreads();
  if (tid < NBr && h[tid]) atomicAdd(&bcount[tid], h[tid]);
}

__global__ __launch_bounds__(256) void bscan_k(const int* __restrict__ bcount,
    int* __restrict__ bstart, int* __restrict__ bcursor, int NBr) {
  __shared__ int sh[256];
  const int t = threadIdx.x;
  sh[t] = (t < NBr) ? bcount[t] : 0;
  __syncthreads();
  for (int off = 1; off < 256; off <<= 1) {
    int w = (t >= off) ? sh[t - off] : 0;
    __syncthreads();
    sh[t] += w;
    __syncthreads();
  }
  if (t < NBr) {
    int ex = t ? sh[t - 1] : 0;
    bstart[t] = ex;
    bcursor[t] = ex;
  }
  if (t == NBr - 1) bstart[NBr] = sh[t];
}

__global__ __launch_bounds__(256) void bscatter_k(const int* __restrict__ ei, int E,
    int* __restrict__ bcursor, unsigned* __restrict__ brec, int NBr) {
  __shared__ int h[256];
  __shared__ int base[256];
  const int tid = threadIdx.x;
  h[tid] = 0;
  __syncthreads();
  const int chunk = (E + gridDim.x - 1) / gridDim.x;
  const int s = blockIdx.x * chunk;
  const int e = min(E, s + chunk);
  for (int t = s + tid; t < e; t += 256) atomicAdd(&h[ei[E + t] >> 8], 1);
  __syncthreads();
  if (tid < NBr && h[tid]) base[tid] = atomicAdd(&bcursor[tid], h[tid]);
  __syncthreads();
  for (int t = s + tid; t < e; t += 256) {
    int src = ei[t];
    int d = ei[E + t];
    int bk = d >> 8;
    int p = atomicAdd(&base[bk], 1);
    brec[p] = ((unsigned)src << 8) | (unsigned)(d & 255);
  }
}

__global__ __launch_bounds__(256) void bcsr_k(const unsigned* __restrict__ brec,
    const int* __restrict__ bstart, int n, int E,
    int* __restrict__ rowptr, int* __restrict__ colidx, float* __restrict__ dinv) {
  __shared__ int s_deg[256];
  __shared__ int s_cur[256];
  __shared__ int s_lrp[257];
  const int b = blockIdx.x, tid = threadIdx.x;
  const int node0 = b << 8;
  const int LC = min(256, n - node0);
  const int rs = bstart[b], cnt = bstart[b + 1] - rs;

  s_deg[tid] = (tid < LC) ? 1 : 0;
  __syncthreads();
  for (int i = tid; i < cnt; i += 256) atomicAdd(&s_deg[brec[rs + i] & 255], 1);
  __syncthreads();
  s_cur[tid] = s_deg[tid];
  __syncthreads();
  for (int off = 1; off < 256; off <<= 1) {
    int w = (tid >= off) ? s_cur[tid - off] : 0;
    __syncthreads();
    s_cur[tid] += w;
    __syncthreads();
  }
  s_lrp[tid + 1] = s_cur[tid];
  if (tid == 0) s_lrp[0] = 0;
  __syncthreads();

  const int gbase = rs + node0;
  if (tid < LC) {
    int p = s_lrp[tid];
    colidx[gbase + p] = node0 + tid;
    s_cur[tid] = p + 1;
    rowptr[node0 + tid] = gbase + p;
    dinv[node0 + tid] = rsqrtf((float)(s_lrp[tid + 1] - p));
  }
  __syncthreads();
  for (int i = tid; i < cnt; i += 256) {
    unsigned r = brec[rs + i];
    int p = atomicAdd(&s_cur[r & 255], 1);
    colidx[gbase + p] = (int)(r >> 8);
  }
  if (b == (int)gridDim.x - 1 && tid == 0) rowptr[n] = E + n;
}

// ================= input convert: fp32 -> fp16 Z =================
__global__ __launch_bounds__(256) void split_k(const float* __restrict__ x,
    __half* __restrict__ z, long total4) {
  long t = (long)blockIdx.x * 256 + threadIdx.x;
  if (t >= total4) return;
  float4 v = reinterpret_cast<const float4*>(x)[t];
  union { __half2 h[2]; uint2 u; } uu;
  uu.h[0] = __floats2half2_rn(v.x, v.y);
  uu.h[1] = __floats2half2_rn(v.z, v.w);
  reinterpret_cast<uint2*>(z)[t] = uu.u;
}

// ====== W prep: fp32 W[k][c] -> fp16 hi/lo, transposed Wt[c][k] ======
__global__ __launch_bounds__(256) void wprep_k(
    const float* __restrict__ W1, const float* __restrict__ W2,
    const float* __restrict__ W3, const float* __restrict__ W4,
    __half* __restrict__ wth, __half* __restrict__ wtl) {
  int id = blockIdx.x * 256 + threadIdx.x;
  if (id >= 57344) return;
  const float* W;
  int nout, base, rem;
  if (id < 49152) {
    int l = id / 16384;
    W = (l == 0) ? W1 : (l == 1) ? W2 : W3;
    nout = 128;
    base = l * 16384;
    rem = id - base;
  } else {
    W = W4;
    nout = 64;
    base = 49152;
    rem = id - base;
  }
  int k = rem / nout, c = rem % nout;
  float w = W[k * nout + c];
  __half hi = __float2half_rn(w);
  __half lo = __float2half_rn(w - __half2float(hi));
  wth[base + c * 128 + k] = hi;
  wtl[base + c * 128 + k] = lo;
}

// ======= MFMA GEMM: H[r] = dinv[r] * (Z @ W)[r]  (fp16 Z, 2-term fp16 W) =======
// 64-row tiles, 4 waves, wave = 16 rows x NOUT cols. LDS XOR-oct-swizzled:
// source k-oct q of row r stored at dest oct q ^ g(r), g(r) = (r + (r>>2)) & 3.
template<int NOUT>
__global__ __launch_bounds__(256) void gemm_mfma_k(
    const __half* __restrict__ Z,
    const __half* __restrict__ Wh, const __half* __restrict__ Wl,
    const float* __restrict__ dinv, __half* __restrict__ H, int n) {
  constexpr int NT = NOUT / 16;
  __shared__ __half Az[64][32];
  __shared__ __half Bh[NOUT][32];
  __shared__ __half Bl[NOUT][32];
  const int tid = threadIdx.x;
  const int lane = tid & 63;
  const int w = tid >> 6;
  const int r16 = lane & 15;
  const int kb = lane >> 4;
  const int row0 = blockIdx.x * 64;
  const int sw = (r16 + (r16 >> 2)) & 3;   // g(row) for all rows this lane reads

  f32x4 acc[NT];
  #pragma unroll
  for (int t = 0; t < NT; ++t)
    #pragma unroll
    for (int q = 0; q < 4; ++q) acc[t][q] = 0.f;

  char* AzB = (char*)&Az[0][0];
  char* BhB = (char*)&Bh[0][0];
  char* BlB = (char*)&Bl[0][0];

  for (int kc = 0; kc < 128; kc += 32) {
    __syncthreads();
    {
      // A: slot=tid -> row r=tid>>2, dest oct j=tid&3, src oct q=j^g(r)
      int r = tid >> 2;
      int q = (tid & 3) ^ ((r + (r >> 2)) & 3);
      int rc = row0 + r; rc = (rc < n) ? rc : (n - 1);
      GLOAD16(Z + (size_t)rc * 128 + kc + q * 8, AzB + w * 1024);
    }
    {
      // B: slot=tid (+256 for NOUT=128) -> col c=slot>>2, same swizzle
      int c = tid >> 2;
      int q = (tid & 3) ^ ((c + (c >> 2)) & 3);
      GLOAD16(Wh + (size_t)c * 128 + kc + q * 8, BhB + w * 1024);
      GLOAD16(Wl + (size_t)c * 128 + kc + q * 8, BlB + w * 1024);
      if constexpr (NOUT == 128) {
        int i1 = tid + 256;
        int c1 = i1 >> 2;
        int q1 = (i1 & 3) ^ ((c1 + (c1 >> 2)) & 3);
        GLOAD16(Wh + (size_t)c1 * 128 + kc + q1 * 8, BhB + 4096 + w * 1024);
        GLOAD16(Wl + (size_t)c1 * 128 + kc + q1 * 8, BlB + 4096 + w * 1024);
      }
    }
    __syncthreads();

    const int ao = (kb ^ sw) * 8;
    f16x8 az = *(const f16x8*)&Az[w * 16 + r16][ao];
    #pragma unroll
    for (int t = 0; t < NT; ++t) {
      f16x8 bh = *(const f16x8*)&Bh[t * 16 + r16][ao];
      f16x8 bl = *(const f16x8*)&Bl[t * 16 + r16][ao];
      acc[t] = __builtin_amdgcn_mfma_f32_16x16x32_f16(az, bh, acc[t], 0, 0, 0);
      acc[t] = __builtin_amdgcn_mfma_f32_16x16x32_f16(az, bl, acc[t], 0, 0, 0);
    }
  }

  // epilogue: H[row] = dinv[row] * acc (fp16); C/D: col=r16, row=kb*4+q
  #pragma unroll
  for (int q = 0; q < 4; ++q) {
    int grow = row0 + w * 16 + kb * 4 + q;
    if (grow < n) {
      float dsc = dinv[grow];
      #pragma unroll
      for (int t = 0; t < NT; ++t)
        H[(size_t)grow * NOUT + t * 16 + r16] = __float2half(dsc * acc[t][q]);
    }
  }
}

// ================= CSR aggregation (prescaled H, shfl-broadcast) =============
// Wave = 1 node, lane = feature pair. H prescaled by dinv[src]:
// out_i = dinv[i] * sum_c H'[c] + b ; relu, fp16 Z store.
__global__ __launch_bounds__(256) void agg128_k(const __half* __restrict__ H,
    const int* __restrict__ rowptr, const int* __restrict__ colidx,
    const float* __restrict__ dinv, const float* __restrict__ bias,
    __half* __restrict__ Z, int n) {
  const int wave = threadIdx.x >> 6;
  const int lane = threadIdx.x & 63;
  const int node = blockIdx.x * 4 + wave;
  if (node >= n) return;
  const int s = rowptr[node], e = rowptr[node + 1];
  const __half2* H2 = reinterpret_cast<const __half2*>(H);

  float ax = 0.f, ay = 0.f;
  for (int base = s; base < e; base += 64) {
    int m = e - base;
    int c = __builtin_nontemporal_load(&colidx[base + ((lane < m) ? lane : 0)]);
    int kmax = (m < 64) ? m : 64;
    int k = 0;
    for (; k + 7 < kmax; k += 8) {
      int cc[8];
      float2 hh[8];
      #pragma unroll
      for (int u = 0; u < 8; ++u) cc[u] = __shfl(c, k + u);
      #pragma unroll
      for (int u = 0; u < 8; ++u) hh[u] = __half22float2(H2[(size_t)cc[u] * 64 + lane]);
      #pragma unroll
      for (int u = 0; u < 8; ++u) { ax += hh[u].x; ay += hh[u].y; }
    }
    for (; k < kmax; ++k) {
      int ck = __shfl(c, k);
      float2 h = __half22float2(H2[(size_t)ck * 64 + lane]);
      ax += h.x;
      ay += h.y;
    }
  }
  float d = dinv[node];
  float2 b2 = reinterpret_cast<const float2*>(bias)[lane];
  float ox = fmaxf(fmaf(d, ax, b2.x), 0.f);
  float oy = fmaxf(fmaf(d, ay, b2.y), 0.f);
  __half2 hv = __floats2half2_rn(ox, oy);
  unsigned vv = *reinterpret_cast<unsigned*>(&hv);
  __builtin_nontemporal_store(vv, reinterpret_cast<unsigned*>(Z) + (size_t)node * 64 + lane);
}

// final layer: 64-wide, fp32 out, no relu
__global__ __launch_bounds__(256) void agg64_k(const __half* __restrict__ H,
    const int* __restrict__ rowptr, const int* __restrict__ colidx,
    const float* __restrict__ dinv, const float* __restrict__ bias,
    float* __restrict__ out, int n) {
  const int wave = threadIdx.x >> 6;
  const int lane = threadIdx.x & 63;
  const int node = blockIdx.x * 4 + wave;
  if (node >= n) return;
  const int s = rowptr[node], e = rowptr[node + 1];

  float a0 = 0.f;
  for (int base = s; base < e; base += 64) {
    int m = e - base;
    int c = __builtin_nontemporal_load(&colidx[base + ((lane < m) ? lane : 0)]);
    int kmax = (m < 64) ? m : 64;
    int k = 0;
    for (; k + 7 < kmax; k += 8) {
      int cc[8];
      float hh[8];
      #pragma unroll
      for (int u = 0; u < 8; ++u) cc[u] = __shfl(c, k + u);
      #pragma unroll
      for (int u = 0; u < 8; ++u) hh[u] = __half2float(H[(size_t)cc[u] * 64 + lane]);
      #pragma unroll
      for (int u = 0; u < 8; ++u) a0 += hh[u];
    }
    for (; k < kmax; ++k) {
      int ck = __shfl(c, k);
      a0 += __half2float(H[(size_t)ck * 64 + lane]);
    }
  }
  float o = fmaf(dinv[node], a0, bias[lane]);
  __builtin_nontemporal_store(o, &out[(size_t)node * 64 + lane]);
}

extern "C" void kernel_launch(void* const* d_in, const int* in_sizes, int n_in,
                              void* d_out, int out_size, void* d_ws, size_t ws_size,
                              hipStream_t stream) {
  const int n = in_sizes[0] / K_DIM;   // 50000
  const int E = in_sizes[1] / 2;       // 1600000
  const int NBr = (n + 255) >> 8;

  const float* x  = (const float*)d_in[0];
  const int*   ei = (const int*)d_in[1];
  const float* W1 = (const float*)d_in[2];
  const float* b1 = (const float*)d_in[3];
  const float* W2 = (const float*)d_in[4];
  const float* b2 = (const float*)d_in[5];
  const float* W3 = (const float*)d_in[6];
  const float* b3 = (const float*)d_in[7];
  const float* W4 = (const float*)d_in[8];
  const float* b4 = (const float*)d_in[9];
  float* out = (float*)d_out;

  char* ws = (char*)d_ws;
  size_t off = 0;
  auto alloc = [&](size_t bytes) -> void* {
    void* p = ws + off;
    off += (bytes + 255) & ~(size_t)255;
    return p;
  };
  int*      bcount  = (int*)     alloc(256 * 4);
  int*      bstart  = (int*)     alloc(257 * 4);
  int*      bcursor = (int*)     alloc(256 * 4);
  unsigned* brec    = (unsigned*)alloc((size_t)E * 4);
  int*      rowptr  = (int*)     alloc((size_t)(n + 1) * 4);
  int*      colidx  = (int*)     alloc((size_t)(E + n) * 4);
  float*    dinv    = (float*)   alloc((size_t)n * 4);
  __half*   Z       = (__half*)  alloc((size_t)n * 128 * 2);   // fp16 gemm input
  __half*   hH      = (__half*)  alloc((size_t)n * 128 * 2);   // fp16 pre-agg (prescaled)
  __half*   wth     = (__half*)  alloc((size_t)57344 * 2);
  __half*   wtl     = (__half*)  alloc((size_t)57344 * 2);

  // CSR build
  zerob_k<<<1, 256, 0, stream>>>(bcount, NBr);
  bcount_k<<<512, 256, 0, stream>>>(ei + E, E, bcount, NBr);
  bscan_k<<<1, 256, 0, stream>>>(bcount, bstart, bcursor, NBr);
  bscatter_k<<<256, 256, 0, stream>>>(ei, E, bcursor, brec, NBr);
  bcsr_k<<<NBr, 256, 0, stream>>>(brec, bstart, n, E, rowptr, colidx, dinv);

  // input convert + weight prep
  const long total4 = (long)n * 32;
  split_k<<<(int)((total4 + 255) / 256), 256, 0, stream>>>(x, Z, total4);
  wprep_k<<<224, 256, 0, stream>>>(W1, W2, W3, W4, wth, wtl);

  const int gb = (n + 63) / 64;   // 782 blocks
  const int ab = (n + 3) / 4;

  // layer 1
  gemm_mfma_k<128><<<gb, 256, 0, stream>>>(Z, wth, wtl, dinv, hH, n);
  agg128_k<<<ab, 256, 0, stream>>>(hH, rowptr, colidx, dinv, b1, Z, n);
  // layer 2
  gemm_mfma_k<128><<<gb, 256, 0, stream>>>(Z, wth + 16384, wtl + 16384, dinv, hH, n);
  agg128_k<<<ab, 256, 0, stream>>>(hH, rowptr, colidx, dinv, b2, Z, n);
  // layer 3
  gemm_mfma_k<128><<<gb, 256, 0, stream>>>(Z, wth + 32768, wtl + 32768, dinv, hH, n);
  agg128_k<<<ab, 256, 0, stream>>>(hH, rowptr, colidx, dinv, b3, Z, n);
  // layer 4 (128 -> 64)
  gemm_mfma_k<64><<<gb, 256, 0, stream>>>(Z, wth + 49152, wtl + 49152, dinv, hH, n);
  agg64_k<<<ab, 256, 0, stream>>>(hH, rowptr, colidx, dinv, b4, out, n);
}